// Round 15
// baseline (65.789 us; speedup 1.0000x reference)
//
#include <hip/hip_runtime.h>

// Problem constants
#define B_    8
#define H_    512
#define W_    512
#define KK_   9
#define COUT_ 3
#define HO_   510
#define WO_   510
#define PLANE_ 260100           // HO_*WO_

__device__ __forceinline__ int iclamp(int v, int lo, int hi) {
    return v < lo ? lo : (v > hi ? hi : v);
}

// Wave = 4x16 output patch (R14-proven). Block = 512 threads = 4 rows x 128 cols.
// R15: depth-1 software pipeline — tap k+1's offset/mask stream loads are issued
// (in program order) before tap k's gathers+compute, so stream latency hides
// under the previous tap's work instead of serializing the per-tap chain.
__global__ __launch_bounds__(512, 4) void dcn_fwd_kernel(
    const float* __restrict__ x,       // [B,1,512,512]
    const float* __restrict__ offset,  // [B,18,510,510]
    const float* __restrict__ mask,    // [B,9,510,510]
    const float* __restrict__ weight,  // [3,1,3,3]
    const float* __restrict__ bias,    // [3]
    float* __restrict__ out)           // [B,3,510,510]
{
    const int bid  = blockIdx.x;       // 4 colblk * 128 band * 8 batch = 4096
    const int wt   = bid & 3;          // col-block (128 cols)
    const int band = (bid >> 2) & 127; // row band (4 rows)
    const int b    = bid >> 9;         // batch

    const int tid  = threadIdx.x;
    const int wave = tid >> 6;         // 0..7
    const int lane = tid & 63;
    const int r    = lane >> 4;        // 0..3
    const int c    = lane & 15;        // 0..15

    const int ho = band * 4 + r;
    const int wo = wt * 128 + wave * 16 + c;
    const bool valid = (ho < HO_) & (wo < WO_);
    const int ho_c = ho < HO_ ? ho : HO_ - 1;
    const int wo_c = wo < WO_ ? wo : WO_ - 1;

    const int pix = ho_c * WO_ + wo_c;
    const float* xb   = x + (b << 18);
    const float* offb = offset + b * (2 * KK_ * PLANE_) + pix;
    const float* mb   = mask   + b * (KK_ * PLANE_)    + pix;

    // weights/bias: uniform addresses -> scalar broadcast loads
    float w0[KK_], w1[KK_], w2[KK_];
    #pragma unroll
    for (int k = 0; k < KK_; ++k) {
        w0[k] = weight[0 * KK_ + k];
        w1[k] = weight[1 * KK_ + k];
        w2[k] = weight[2 * KK_ + k];
    }
    const float b0 = bias[0], b1 = bias[1], b2 = bias[2];

    const float fho = (float)ho_c;
    const float fwo = (float)wo_c;

    float acc0 = 0.f, acc1 = 0.f, acc2 = 0.f;

    // ---- prologue: tap 0 streams ----
    float dy = offb[0];
    float dx = offb[PLANE_];
    float m  = mb[0];

    #pragma unroll
    for (int kk = 0; kk < KK_; ++kk) {
        // issue next tap's stream loads FIRST (depth-1 pipeline)
        float dyN = 0.f, dxN = 0.f, mN = 0.f;
        if (kk < KK_ - 1) {
            dyN = offb[(2 * kk + 2) * PLANE_];
            dxN = offb[(2 * kk + 3) * PLANE_];
            mN  = mb  [(kk + 1)     * PLANE_];
        }

        // compute current tap
        const int kh = kk / 3, kw = kk % 3;
        const float py = (fho + (float)kh) + dy;
        const float px = (fwo + (float)kw) + dx;

        const float y0f = floorf(py);
        const float x0f = floorf(px);
        const float ly  = py - y0f;
        const float lx  = px - x0f;
        const float y1f = y0f + 1.0f;
        const float x1f = x0f + 1.0f;

        // validity on UNCLIPPED float corner coords (reference semantics)
        const float vy0 = (y0f >= 0.f && y0f <= 511.f) ? 1.f : 0.f;
        const float vy1 = (y1f >= 0.f && y1f <= 511.f) ? 1.f : 0.f;
        const float vx0 = (x0f >= 0.f && x0f <= 511.f) ? 1.f : 0.f;
        const float vx1 = (x1f >= 0.f && x1f <= 511.f) ? 1.f : 0.f;

        const int yi0 = iclamp((int)y0f, 0, 511);
        const int yi1 = iclamp((int)y1f, 0, 511);
        const int xi0 = iclamp((int)x0f, 0, 511);
        const int xi1 = iclamp((int)x1f, 0, 511);

        const float v00 = xb[(yi0 << 9) + xi0] * (vy0 * vx0);
        const float v01 = xb[(yi0 << 9) + xi1] * (vy0 * vx1);
        const float v10 = xb[(yi1 << 9) + xi0] * (vy1 * vx0);
        const float v11 = xb[(yi1 << 9) + xi1] * (vy1 * vx1);

        const float top = fmaf(lx, v01 - v00, v00);
        const float bot = fmaf(lx, v11 - v10, v10);
        const float val = fmaf(ly, bot - top, top);
        const float s   = val * m;
        acc0 = fmaf(w0[kk], s, acc0);
        acc1 = fmaf(w1[kk], s, acc1);
        acc2 = fmaf(w2[kk], s, acc2);

        // rotate
        dy = dyN; dx = dxN; m = mN;
    }

    if (valid) {
        const int ob = b * (COUT_ * PLANE_) + pix;
        out[ob]              = acc0 + b0;
        out[ob + PLANE_]     = acc1 + b1;
        out[ob + 2 * PLANE_] = acc2 + b2;
    }
}

extern "C" void kernel_launch(void* const* d_in, const int* in_sizes, int n_in,
                              void* d_out, int out_size, void* d_ws, size_t ws_size,
                              hipStream_t stream) {
    const float* x      = (const float*)d_in[0];
    const float* offset = (const float*)d_in[1];
    const float* mask   = (const float*)d_in[2];
    const float* weight = (const float*)d_in[3];
    const float* bias   = (const float*)d_in[4];
    float* out = (float*)d_out;

    const int grid = 4 * 128 * B_;   // colblk x band x batch = 4096
    dcn_fwd_kernel<<<grid, 512, 0, stream>>>(x, offset, mask, weight, bias, out);
}

// Round 16
// 57.313 us; speedup vs baseline: 1.1479x; 1.1479x over previous
//
#include <hip/hip_runtime.h>

// Problem constants
#define B_    8
#define H_    512
#define W_    512
#define KK_   9
#define COUT_ 3
#define HO_   510
#define WO_   510
#define PLANE_ 260100           // HO_*WO_

__device__ __forceinline__ int iclamp(int v, int lo, int hi) {
    return v < lo ? lo : (v > hi ? hi : v);
}

// 4-byte-aligned float2: lets the compiler emit one dwordx2 load at any
// dword-aligned address (gfx950 global loads support unaligned access).
typedef float f2a __attribute__((ext_vector_type(2), aligned(4)));

// Wave = 4x16 output patch (R14-proven). Block = 512 threads = 4 rows x 128 cols.
// R16: horizontal corner pairs (y,x0),(y,x0+1) fused into ONE 8B load per row:
// 36 gather instrs/wave -> 18. Edge cases handled by branchless selects:
//   v00 = (x0>=511) ? q.y : q.x     (x0==511: clamp gives load at 510, x[511]=q.y)
//   v01 = (x0<0)    ? q.x : q.y     (x0==-1:  clamp gives load at 0,   x[0]  =q.x)
// selected values only matter where the corresponding validity != 0.
__global__ __launch_bounds__(512, 4) void dcn_fwd_kernel(
    const float* __restrict__ x,       // [B,1,512,512]
    const float* __restrict__ offset,  // [B,18,510,510]
    const float* __restrict__ mask,    // [B,9,510,510]
    const float* __restrict__ weight,  // [3,1,3,3]
    const float* __restrict__ bias,    // [3]
    float* __restrict__ out)           // [B,3,510,510]
{
    const int bid  = blockIdx.x;       // 4 colblk * 128 band * 8 batch = 4096
    const int wt   = bid & 3;          // col-block (128 cols)
    const int band = (bid >> 2) & 127; // row band (4 rows)
    const int b    = bid >> 9;         // batch

    const int tid  = threadIdx.x;
    const int wave = tid >> 6;         // 0..7
    const int lane = tid & 63;
    const int r    = lane >> 4;        // 0..3
    const int c    = lane & 15;        // 0..15

    const int ho = band * 4 + r;
    const int wo = wt * 128 + wave * 16 + c;
    const bool valid = (ho < HO_) & (wo < WO_);
    const int ho_c = ho < HO_ ? ho : HO_ - 1;
    const int wo_c = wo < WO_ ? wo : WO_ - 1;

    const int pix = ho_c * WO_ + wo_c;
    const float* xb   = x + (b << 18);
    const float* offb = offset + b * (2 * KK_ * PLANE_) + pix;
    const float* mb   = mask   + b * (KK_ * PLANE_)    + pix;

    // weights/bias: uniform addresses -> scalar broadcast loads
    float w0[KK_], w1[KK_], w2[KK_];
    #pragma unroll
    for (int k = 0; k < KK_; ++k) {
        w0[k] = weight[0 * KK_ + k];
        w1[k] = weight[1 * KK_ + k];
        w2[k] = weight[2 * KK_ + k];
    }
    const float b0 = bias[0], b1 = bias[1], b2 = bias[2];

    const float fho = (float)ho_c;
    const float fwo = (float)wo_c;

    float acc0 = 0.f, acc1 = 0.f, acc2 = 0.f;

    #pragma unroll
    for (int kh = 0; kh < 3; ++kh) {
        #pragma unroll
        for (int kw = 0; kw < 3; ++kw) {
            const int kk = kh * 3 + kw;
            const float dy = offb[(2 * kk)     * PLANE_];
            const float dx = offb[(2 * kk + 1) * PLANE_];
            const float m  = mb  [ kk          * PLANE_];

            const float py = (fho + (float)kh) + dy;
            const float px = (fwo + (float)kw) + dx;

            const float y0f = floorf(py);
            const float x0f = floorf(px);
            const float ly  = py - y0f;
            const float lx  = px - x0f;
            const float y1f = y0f + 1.0f;
            const float x1f = x0f + 1.0f;

            // validity on UNCLIPPED float corner coords (reference semantics)
            const float vy0 = (y0f >= 0.f && y0f <= 511.f) ? 1.f : 0.f;
            const float vy1 = (y1f >= 0.f && y1f <= 511.f) ? 1.f : 0.f;
            const float vx0 = (x0f >= 0.f && x0f <= 511.f) ? 1.f : 0.f;
            const float vx1 = (x1f >= 0.f && x1f <= 511.f) ? 1.f : 0.f;

            const int iy0 = (int)y0f;
            const int ix0 = (int)x0f;
            const int yi0 = iclamp(iy0,     0, 511);
            const int yi1 = iclamp(iy0 + 1, 0, 511);
            const int xc0 = iclamp(ix0,     0, 510);   // f2 covers {xc0, xc0+1} in-bounds

            // one 8B load per row: both horizontal corners
            const f2a q0 = *(const f2a*)(xb + (yi0 << 9) + xc0);
            const f2a q1 = *(const f2a*)(xb + (yi1 << 9) + xc0);

            const bool hi = (x0f >= 511.f);
            const bool lo = (x0f < 0.f);

            float v00 = (hi ? q0.y : q0.x) * (vy0 * vx0);
            float v01 = (lo ? q0.x : q0.y) * (vy0 * vx1);
            float v10 = (hi ? q1.y : q1.x) * (vy1 * vx0);
            float v11 = (lo ? q1.x : q1.y) * (vy1 * vx1);

            const float top = fmaf(lx, v01 - v00, v00);
            const float bot = fmaf(lx, v11 - v10, v10);
            const float val = fmaf(ly, bot - top, top);
            const float s   = val * m;
            acc0 = fmaf(w0[kk], s, acc0);
            acc1 = fmaf(w1[kk], s, acc1);
            acc2 = fmaf(w2[kk], s, acc2);
        }
    }

    if (valid) {
        const int ob = b * (COUT_ * PLANE_) + pix;
        out[ob]              = acc0 + b0;
        out[ob + PLANE_]     = acc1 + b1;
        out[ob + 2 * PLANE_] = acc2 + b2;
    }
}

extern "C" void kernel_launch(void* const* d_in, const int* in_sizes, int n_in,
                              void* d_out, int out_size, void* d_ws, size_t ws_size,
                              hipStream_t stream) {
    const float* x      = (const float*)d_in[0];
    const float* offset = (const float*)d_in[1];
    const float* mask   = (const float*)d_in[2];
    const float* weight = (const float*)d_in[3];
    const float* bias   = (const float*)d_in[4];
    float* out = (float*)d_out;

    const int grid = 4 * 128 * B_;   // colblk x band x batch = 4096
    dcn_fwd_kernel<<<grid, 512, 0, stream>>>(x, offset, mask, weight, bias, out);
}